// Round 1
// baseline (596.074 us; speedup 1.0000x reference)
//
#include <hip/hip_runtime.h>

typedef unsigned short ushort_t;
typedef unsigned int uint_t;
typedef __bf16 bf16x8 __attribute__((ext_vector_type(8)));
typedef float float4v __attribute__((ext_vector_type(4)));

#define EPS 1e-6f

// Workspace layout (bytes)
#define WS_STYLE   0            // 16*512 f32 = 32 KB
#define WS_INVD    32768        // 16*512 f32 = 32 KB
#define WS_WSQ     65536        // 512*512 f32 = 1 MB
#define WS_AW      1114112      // 512*4608 bf16 = 4,718,592 B
#define WS_XP      6291456      // 16*66*66*512 bf16 = 71,368,704 B
#define XP_BYTES   71368704

__device__ __forceinline__ ushort_t f2bf(float v) {
    union { float f; uint_t u; } c; c.f = v;
    uint_t u = c.u;
    u += 0x7fffu + ((u >> 16) & 1u);   // round-to-nearest-even
    return (ushort_t)(u >> 16);
}

__device__ __forceinline__ void gload_lds16(const void* g, void* l) {
    __builtin_amdgcn_global_load_lds(
        (const __attribute__((address_space(1))) uint_t*)g,
        (__attribute__((address_space(3))) uint_t*)l, 16, 0, 0);
}

// ---------------- P1: style[b][o] = w[b,:] . lw[o,:] + lb[o] ----------------
__global__ void compute_style(const float* __restrict__ w, const float* __restrict__ lw,
                              const float* __restrict__ lb, float* __restrict__ style) {
    int gw = blockIdx.x * 4 + (threadIdx.x >> 6);   // 0..8191
    int lane = threadIdx.x & 63;
    int b = gw >> 9, o = gw & 511;
    float s = 0.f;
#pragma unroll
    for (int j = 0; j < 8; ++j) {
        int d = j * 64 + lane;
        s += w[b * 512 + d] * lw[o * 512 + d];
    }
#pragma unroll
    for (int off = 32; off; off >>= 1) s += __shfl_down(s, off);
    if (lane == 0) style[gw] = s + lb[o];
}

// ------- P2: cast conv weight to bf16 [o][t*512+i]; wsq[o][i] = sum_t cw^2 -------
__global__ void prep_weights(const float* __restrict__ cw, ushort_t* __restrict__ Aw,
                             float* __restrict__ wsq) {
    int id = blockIdx.x * 256 + threadIdx.x;        // o*512 + i
    int o = id >> 9, i = id & 511;
    const float* p = cw + (size_t)id * 9;
    float s = 0.f;
#pragma unroll
    for (int t = 0; t < 9; ++t) {
        float v = p[t];
        s += v * v;
        Aw[(size_t)o * 4608 + t * 512 + i] = f2bf(v);
    }
    wsq[id] = s;
}

// ------- P3: inv_denom[b][o] = rsqrt(sum_i wsq[o][i]*style[b][i]^2 + eps) -------
__global__ void compute_invd(const float* __restrict__ wsq, const float* __restrict__ style,
                             float* __restrict__ invd) {
    int gw = blockIdx.x * 4 + (threadIdx.x >> 6);
    int lane = threadIdx.x & 63;
    int b = gw >> 9, o = gw & 511;
    float s = 0.f;
#pragma unroll
    for (int j = 0; j < 8; ++j) {
        int d = j * 64 + lane;
        float st = style[b * 512 + d];
        s += wsq[o * 512 + d] * st * st;
    }
#pragma unroll
    for (int off = 32; off; off >>= 1) s += __shfl_down(s, off);
    if (lane == 0) invd[gw] = rsqrtf(s + EPS);
}

// ------- P4: Xp[b][y+1][x+1][i] = bf16(x[b][i][y][x] * style[b][i]) (NHWC, pad 1) -------
__global__ void modulate_transpose(const float* __restrict__ x, const float* __restrict__ style,
                                   ushort_t* __restrict__ Xp) {
    __shared__ ushort_t tile[64][65];
    int y = blockIdx.x;           // 0..63
    int i0 = blockIdx.y * 64;     // 0..7 tiles
    int b = blockIdx.z;           // 0..15
    int sub = threadIdx.x >> 6;   // 0..3
    int lane = threadIdx.x & 63;
#pragma unroll
    for (int pass = 0; pass < 16; ++pass) {
        int ir = pass * 4 + sub;
        float s = style[b * 512 + i0 + ir];
        float v = x[(((size_t)b * 512 + i0 + ir) * 64 + y) * 64 + lane] * s;
        tile[ir][lane] = f2bf(v);
    }
    __syncthreads();
    size_t rowbase = ((size_t)b * 66 + (y + 1)) * 66;
#pragma unroll
    for (int pass = 0; pass < 16; ++pass) {
        int xx = pass * 4 + sub;
        Xp[(rowbase + xx + 1) * 512 + i0 + lane] = tile[lane][xx];
    }
}

// ---------------- Main implicit-GEMM conv: per batch M=512, N=4096, K=4608 ----------------
// A = Aw [o][k], k = t*512+i (bf16).  B = im2col of Xp (padded NHWC bf16).
// Tile 128x128, BK=32, 256 threads (4 waves 2x2), mfma_f32_16x16x32_bf16.
__global__ __launch_bounds__(256) void conv_gemm(const ushort_t* __restrict__ Aw,
                                                 const ushort_t* __restrict__ Xp,
                                                 const float* __restrict__ invd,
                                                 float* __restrict__ out) {
    __shared__ ushort_t As[128 * 32];   // [o_local][k_local], 64 B rows
    __shared__ ushort_t Bs[128 * 32];   // [p_local][k_local], 64 B rows

    const int tid = threadIdx.x;
    const int lane = tid & 63;
    const int wave = tid >> 6;
    const int b = blockIdx.z;
    const int o0 = blockIdx.y * 128;
    const int p0 = blockIdx.x * 128;
    const int wm = (wave & 1) * 64;
    const int wn = (wave >> 1) * 64;
    const int l15 = lane & 15;
    const int quad = lane >> 4;

    // per-thread staging bases: lane-load index q = s*256 + tid covers (row=q>>2, chunk=q&3)
    const char* Ab = (const char*)Aw;
    const char* Xb = (const char*)Xp;
    const char* aga[2];
    const char* bga[2];
#pragma unroll
    for (int s = 0; s < 2; ++s) {
        int q = tid + s * 256;
        int row = q >> 2, c = q & 3;
        aga[s] = Ab + (size_t)(o0 + row) * 9216 + c * 16;
        int p = p0 + row;
        int py = p >> 6, px = p & 63;
        size_t pix = ((size_t)b * 66 + (py + 1)) * 66 + (px + 1);  // center pixel, padded
        bga[s] = Xb + pix * 1024 + c * 16;
    }
    // wave-uniform LDS byte offsets for the two staging rounds
    const int lds0 = (wave * 64) * 16;
    const int lds1 = (wave * 64 + 256) * 16;

    float4v acc[4][4] = {};

    for (int kb = 0; kb < 144; ++kb) {
        int t = kb >> 4;                      // tap 0..8
        int dh = t / 3, dw = t % 3;
        long dpix = (long)((dh - 1) * 66 + (dw - 1));
        long boff = dpix * 1024 + (long)(kb & 15) * 64;  // pixel shift + i0*2 bytes
        long aoff = (long)kb * 64;

        __syncthreads();   // previous compute done reading LDS
        gload_lds16(aga[0] + aoff, (char*)As + lds0);
        gload_lds16(aga[1] + aoff, (char*)As + lds1);
        gload_lds16(bga[0] + boff, (char*)Bs + lds0);
        gload_lds16(bga[1] + boff, (char*)Bs + lds1);
        __syncthreads();   // drains vmcnt before barrier

        bf16x8 av[4], bv[4];
#pragma unroll
        for (int mi = 0; mi < 4; ++mi)
            av[mi] = *(const bf16x8*)(As + (wm + mi * 16 + l15) * 32 + quad * 8);
#pragma unroll
        for (int ni = 0; ni < 4; ++ni)
            bv[ni] = *(const bf16x8*)(Bs + (wn + ni * 16 + l15) * 32 + quad * 8);
#pragma unroll
        for (int mi = 0; mi < 4; ++mi)
#pragma unroll
            for (int ni = 0; ni < 4; ++ni)
                acc[mi][ni] = __builtin_amdgcn_mfma_f32_16x16x32_bf16(av[mi], bv[ni], acc[mi][ni], 0, 0, 0);
    }

    // epilogue: out[b][o][p] = acc * inv_denom[b][o]
    const float* invb = invd + b * 512 + o0;
    float* outb = out + ((size_t)b * 512 + o0) * 4096 + p0;
#pragma unroll
    for (int mi = 0; mi < 4; ++mi) {
#pragma unroll
        for (int r = 0; r < 4; ++r) {
            int m = wm + mi * 16 + quad * 4 + r;
            float d = invb[m];
#pragma unroll
            for (int ni = 0; ni < 4; ++ni) {
                int n = wn + ni * 16 + l15;
                outb[(size_t)m * 4096 + n] = acc[mi][ni][r] * d;
            }
        }
    }
}

extern "C" void kernel_launch(void* const* d_in, const int* in_sizes, int n_in,
                              void* d_out, int out_size, void* d_ws, size_t ws_size,
                              hipStream_t stream) {
    const float* x  = (const float*)d_in[0];   // (16,512,64,64)
    const float* w  = (const float*)d_in[1];   // (16,512)
    const float* cw = (const float*)d_in[2];   // (512,512,3,3)
    const float* lw = (const float*)d_in[3];   // (512,512)
    const float* lb = (const float*)d_in[4];   // (512,)
    float* out = (float*)d_out;

    char* ws = (char*)d_ws;
    float*    style = (float*)(ws + WS_STYLE);
    float*    invd  = (float*)(ws + WS_INVD);
    float*    wsq   = (float*)(ws + WS_WSQ);
    ushort_t* Aw    = (ushort_t*)(ws + WS_AW);
    ushort_t* Xp    = (ushort_t*)(ws + WS_XP);

    hipMemsetAsync(Xp, 0, XP_BYTES, stream);                    // zero padding (ws is poisoned)
    compute_style<<<2048, 256, 0, stream>>>(w, lw, lb, style);
    prep_weights<<<1024, 256, 0, stream>>>(cw, Aw, wsq);
    compute_invd<<<2048, 256, 0, stream>>>(wsq, style, invd);
    dim3 g4(64, 8, 16);
    modulate_transpose<<<g4, 256, 0, stream>>>(x, style, Xp);
    dim3 gg(32, 4, 16);
    conv_gemm<<<gg, 256, 0, stream>>>(Aw, Xp, invd, out);
}

// Round 2
// 581.404 us; speedup vs baseline: 1.0252x; 1.0252x over previous
//
#include <hip/hip_runtime.h>

typedef unsigned short ushort_t;
typedef unsigned int uint_t;
typedef __bf16 bf16x8 __attribute__((ext_vector_type(8)));
typedef float float4v __attribute__((ext_vector_type(4)));
typedef uint_t uint4v __attribute__((ext_vector_type(4)));

#define EPS 1e-6f

// Workspace layout (bytes)
#define WS_STYLE   0            // 16*512 f32 = 32 KB
#define WS_INVD    32768        // 16*512 f32 = 32 KB
#define WS_WSQ     65536        // 512*512 f32 = 1 MB
#define WS_AW      1114112      // 512*4608 bf16 = 4,718,592 B
#define WS_XP      6291456      // 16*66*66*512 bf16 = 71,368,704 B

__device__ __forceinline__ ushort_t f2bf(float v) {
    union { float f; uint_t u; } c; c.f = v;
    uint_t u = c.u;
    u += 0x7fffu + ((u >> 16) & 1u);   // round-to-nearest-even
    return (ushort_t)(u >> 16);
}

__device__ __forceinline__ void gload_lds16(const void* g, void* l) {
    __builtin_amdgcn_global_load_lds(
        (const __attribute__((address_space(1))) uint_t*)g,
        (__attribute__((address_space(3))) uint_t*)l, 16, 0, 0);
}

// ---------------- P1: style[b][o] = w[b,:] . lw[o,:] + lb[o] ----------------
__global__ void compute_style(const float* __restrict__ w, const float* __restrict__ lw,
                              const float* __restrict__ lb, float* __restrict__ style) {
    int gw = blockIdx.x * 4 + (threadIdx.x >> 6);   // 0..8191
    int lane = threadIdx.x & 63;
    int b = gw >> 9, o = gw & 511;
    float s = 0.f;
#pragma unroll
    for (int j = 0; j < 8; ++j) {
        int d = j * 64 + lane;
        s += w[b * 512 + d] * lw[o * 512 + d];
    }
#pragma unroll
    for (int off = 32; off; off >>= 1) s += __shfl_down(s, off);
    if (lane == 0) style[gw] = s + lb[o];
}

// ------- P2: cast conv weight to bf16 [o][t*512+i]; wsq[o][i] = sum_t cw^2 -------
__global__ void prep_weights(const float* __restrict__ cw, ushort_t* __restrict__ Aw,
                             float* __restrict__ wsq) {
    int id = blockIdx.x * 256 + threadIdx.x;        // o*512 + i
    int o = id >> 9, i = id & 511;
    const float* p = cw + (size_t)id * 9;
    float s = 0.f;
#pragma unroll
    for (int t = 0; t < 9; ++t) {
        float v = p[t];
        s += v * v;
        Aw[(size_t)o * 4608 + t * 512 + i] = f2bf(v);
    }
    wsq[id] = s;
}

// ------- P3: inv_denom[b][o] = rsqrt(sum_i wsq[o][i]*style[b][i]^2 + eps) -------
__global__ void compute_invd(const float* __restrict__ wsq, const float* __restrict__ style,
                             float* __restrict__ invd) {
    int gw = blockIdx.x * 4 + (threadIdx.x >> 6);
    int lane = threadIdx.x & 63;
    int b = gw >> 9, o = gw & 511;
    float s = 0.f;
#pragma unroll
    for (int j = 0; j < 8; ++j) {
        int d = j * 64 + lane;
        float st = style[b * 512 + d];
        s += wsq[o * 512 + d] * st * st;
    }
#pragma unroll
    for (int off = 32; off; off >>= 1) s += __shfl_down(s, off);
    if (lane == 0) invd[gw] = rsqrtf(s + EPS);
}

// ------- P4a: zero the 1-px padding border of Xp (NHWC, 66x66) -------
__global__ void zero_border(ushort_t* __restrict__ Xp) {
    int bp = blockIdx.x;          // 0..259
    int b = blockIdx.y;
    int lane = threadIdx.x;       // 64 lanes x 16 B = 1024 B = 512 ch
    int py, px;
    if (bp < 66)       { py = 0;        px = bp; }
    else if (bp < 132) { py = 65;       px = bp - 66; }
    else if (bp < 196) { py = bp - 131; px = 0; }
    else               { py = bp - 195; px = 65; }
    size_t pix = ((size_t)b * 66 + py) * 66 + px;
    ((uint4v*)(Xp + pix * 512))[lane] = (uint4v){0, 0, 0, 0};
}

// ------- P4b: Xp[b][y+1][x+1][i] = bf16(x[b][i][y][x] * style[b][i]) (NHWC interior) -------
__global__ void modulate_transpose(const float* __restrict__ x, const float* __restrict__ style,
                                   ushort_t* __restrict__ Xp) {
    __shared__ ushort_t tile[64][65];   // [i_local][x]
    int y = blockIdx.x;           // 0..63
    int i0 = blockIdx.y * 64;     // 8 tiles of 64 channels
    int b = blockIdx.z;           // 0..15
    int tid = threadIdx.x;
    int sub = tid >> 6;           // 0..3 (wave)
    int lane = tid & 63;          // x position
#pragma unroll
    for (int pass = 0; pass < 16; ++pass) {
        int ir = pass * 4 + sub;
        float s = style[b * 512 + i0 + ir];
        float v = x[(((size_t)b * 512 + i0 + ir) * 64 + y) * 64 + lane] * s;
        tile[ir][lane] = f2bf(v);
    }
    __syncthreads();
    size_t rowbase = ((size_t)b * 66 + (y + 1)) * 66 + 1;
#pragma unroll
    for (int pass = 0; pass < 2; ++pass) {
        int idx = pass * 256 + tid;
        int xx = idx >> 3;        // 0..63
        int ch8 = idx & 7;        // 8-channel chunk
        ushort_t v[8];
#pragma unroll
        for (int j = 0; j < 8; ++j) v[j] = tile[ch8 * 8 + j][xx];
        *(uint4v*)(Xp + (rowbase + xx) * 512 + i0 + ch8 * 8) = *(uint4v*)v;
    }
}

// ---------------- Main implicit-GEMM conv: per batch M=512, N=4096, K=4608 ----------------
// A = Aw [o][k], k = t*512+i (bf16).  B = im2col of Xp (padded NHWC bf16).
// Tile 128x128, BK=32, 256 threads (4 waves 2x2), mfma_f32_16x16x32_bf16.
// LDS rows are 64 B (4 granules of 16 B); granule slot XOR-swizzled by ((row>>1)&3)
// so ds_read_b128 hits all 8 granule slots 2-way (free) instead of 8-way.
__global__ __launch_bounds__(256) void conv_gemm(const ushort_t* __restrict__ Aw,
                                                 const ushort_t* __restrict__ Xp,
                                                 const float* __restrict__ invd,
                                                 float* __restrict__ out) {
    __shared__ ushort_t As[128 * 32];   // [o_local][k_local], swizzled granules
    __shared__ ushort_t Bs[128 * 32];   // [p_local][k_local], swizzled granules

    const int tid = threadIdx.x;
    const int lane = tid & 63;
    const int wave = tid >> 6;
    const int b = blockIdx.z;
    const int o0 = blockIdx.y * 128;
    const int p0 = blockIdx.x * 128;
    const int wm = (wave & 1) * 64;
    const int wn = (wave >> 1) * 64;
    const int l15 = lane & 15;
    const int quad = lane >> 4;

    // staging: lane-load q = s*256 + tid fills LDS granule q (linear).
    // granule q = (row = q>>2, slot = q&3); slot holds global chunk c = slot ^ ((row>>1)&3)
    const char* Ab = (const char*)Aw;
    const char* Xb = (const char*)Xp;
    const char* aga[2];
    const char* bga[2];
#pragma unroll
    for (int s = 0; s < 2; ++s) {
        int q = tid + s * 256;
        int row = q >> 2;
        int c = (q & 3) ^ ((q >> 3) & 3);
        aga[s] = Ab + (size_t)(o0 + row) * 9216 + c * 16;
        int p = p0 + row;
        int py = p >> 6, px = p & 63;
        size_t pix = ((size_t)b * 66 + (py + 1)) * 66 + (px + 1);  // center pixel, padded
        bga[s] = Xb + pix * 1024 + c * 16;
    }
    const int lds0 = (wave * 64) * 16;
    const int lds1 = (wave * 64 + 256) * 16;

    // read-side swizzle: row = (16-aligned) + l15 -> slot = quad ^ ((l15>>1)&3)
    const int sw = (quad ^ ((l15 >> 1) & 3)) * 8;   // ushort offset within row

    float4v acc[4][4] = {};

    for (int kb = 0; kb < 144; ++kb) {
        int t = kb >> 4;                      // tap 0..8
        int dh = t / 3, dw = t % 3;
        long dpix = (long)((dh - 1) * 66 + (dw - 1));
        long boff = dpix * 1024 + (long)(kb & 15) * 64;  // pixel shift + i0*2 bytes
        long aoff = (long)kb * 64;

        __syncthreads();   // previous compute done reading LDS
        gload_lds16(aga[0] + aoff, (char*)As + lds0);
        gload_lds16(aga[1] + aoff, (char*)As + lds1);
        gload_lds16(bga[0] + boff, (char*)Bs + lds0);
        gload_lds16(bga[1] + boff, (char*)Bs + lds1);
        __syncthreads();   // drains vmcnt before barrier

        bf16x8 av[4], bv[4];
#pragma unroll
        for (int mi = 0; mi < 4; ++mi)
            av[mi] = *(const bf16x8*)(As + (wm + mi * 16 + l15) * 32 + sw);
#pragma unroll
        for (int ni = 0; ni < 4; ++ni)
            bv[ni] = *(const bf16x8*)(Bs + (wn + ni * 16 + l15) * 32 + sw);
#pragma unroll
        for (int mi = 0; mi < 4; ++mi)
#pragma unroll
            for (int ni = 0; ni < 4; ++ni)
                acc[mi][ni] = __builtin_amdgcn_mfma_f32_16x16x32_bf16(av[mi], bv[ni], acc[mi][ni], 0, 0, 0);
    }

    // epilogue: out[b][o][p] = acc * inv_denom[b][o]
    const float* invb = invd + b * 512 + o0;
    float* outb = out + ((size_t)b * 512 + o0) * 4096 + p0;
#pragma unroll
    for (int mi = 0; mi < 4; ++mi) {
#pragma unroll
        for (int r = 0; r < 4; ++r) {
            int m = wm + mi * 16 + quad * 4 + r;
            float d = invb[m];
#pragma unroll
            for (int ni = 0; ni < 4; ++ni) {
                int n = wn + ni * 16 + l15;
                outb[(size_t)m * 4096 + n] = acc[mi][ni][r] * d;
            }
        }
    }
}

extern "C" void kernel_launch(void* const* d_in, const int* in_sizes, int n_in,
                              void* d_out, int out_size, void* d_ws, size_t ws_size,
                              hipStream_t stream) {
    const float* x  = (const float*)d_in[0];   // (16,512,64,64)
    const float* w  = (const float*)d_in[1];   // (16,512)
    const float* cw = (const float*)d_in[2];   // (512,512,3,3)
    const float* lw = (const float*)d_in[3];   // (512,512)
    const float* lb = (const float*)d_in[4];   // (512,)
    float* out = (float*)d_out;

    char* ws = (char*)d_ws;
    float*    style = (float*)(ws + WS_STYLE);
    float*    invd  = (float*)(ws + WS_INVD);
    float*    wsq   = (float*)(ws + WS_WSQ);
    ushort_t* Aw    = (ushort_t*)(ws + WS_AW);
    ushort_t* Xp    = (ushort_t*)(ws + WS_XP);

    compute_style<<<2048, 256, 0, stream>>>(w, lw, lb, style);
    prep_weights<<<1024, 256, 0, stream>>>(cw, Aw, wsq);
    compute_invd<<<2048, 256, 0, stream>>>(wsq, style, invd);
    dim3 gz(260, 16);
    zero_border<<<gz, 64, 0, stream>>>(Xp);
    dim3 g4(64, 8, 16);
    modulate_transpose<<<g4, 256, 0, stream>>>(x, style, Xp);
    dim3 gg(32, 4, 16);
    conv_gemm<<<gg, 256, 0, stream>>>(Aw, Xp, invd, out);
}